// Round 8
// baseline (1246.867 us; speedup 1.0000x reference)
//
#include <hip/hip_runtime.h>
#include <hip/hip_bf16.h>
#include <math.h>

// Split-bf16 MFMA exact-KNN (K=32) + inverse-squared-distance weighting.
// points:[16384,64] features:[20000,64] targets:[20000] -> out:[16384]
//
// Round 8: LDS-staged feature stream via global_load_lds (async DMA),
// fragment-major LDS layout (lane-linear ds_read_b128, conflict-free),
// double-buffered chunk-pairs, 1 barrier/pair. Sample values in registers,
// tau via 16-step bit-descent + cross-wave count reduce (no smp LDS).
// Filter-then-rank selection (R6) unchanged.

#define NQ   16384
#define MM   20000
#define DD   64
#define KK   32
#define MPAD 20096
#define NCH  (MPAD / 64)   // 314 chunks
#define NP2  (NCH / 2)     // 157 pairs (full scan)
#define NP1  16            // sample pairs = chunks 0..31 = rows 0..2047
#define NW   8
#define CAP  768

typedef __attribute__((ext_vector_type(8))) short bf16x8;
typedef __attribute__((ext_vector_type(4))) float f32x4;

// ---- workspace layout (bytes) ----
#define OFF_FH 0
#define SZ_FP  (MPAD * DD * 2)
#define OFF_FL (OFF_FH + SZ_FP)
#define OFF_FN (OFF_FL + SZ_FP)
#define SZ_FN  (MPAD * 4)
#define OFF_QH (OFF_FN + SZ_FN)
#define SZ_QP  (NQ * DD * 2)
#define OFF_QL (OFF_QH + SZ_QP)
#define OFF_QN (OFF_QL + SZ_QP)
#define SZ_QN  (NQ * 4)
#define WS_REQ (OFF_QN + SZ_QN)

__device__ __forceinline__ unsigned int bf16_rne(float x) {
    unsigned int xb = __float_as_uint(x);
    return (xb + 0x7fffu + ((xb >> 16) & 1u)) & 0xffff0000u;
}
__device__ __forceinline__ unsigned enc32(float f) {
    unsigned b = __float_as_uint(f);
    return (b & 0x80000000u) ? ~b : (b | 0x80000000u);
}
__device__ __forceinline__ float dec32(unsigned k) {
    unsigned b = (k & 0x80000000u) ? (k & 0x7FFFFFFFu) : ~k;
    return __uint_as_float(b);
}

__global__ void prep_split(const float* __restrict__ src,
                           unsigned short* __restrict__ ph,
                           unsigned short* __restrict__ pl,
                           float* __restrict__ nrm, int nrows_real) {
    const int e = blockIdx.x * 256 + threadIdx.x;
    const int m = e >> 6;
    const int lane = threadIdx.x & 63;
    const bool real = (m < nrows_real);
    float x = real ? src[e] : 0.f;
    unsigned int hb = bf16_rne(x);
    float xh = __uint_as_float(hb);
    unsigned int lb = bf16_rne(x - xh);
    ph[e] = (unsigned short)(hb >> 16);
    pl[e] = (unsigned short)(lb >> 16);
    float s = x * x;
    #pragma unroll
    for (int o = 32; o >= 1; o >>= 1) s += __shfl_xor(s, o);
    if (lane == 0) nrm[m] = real ? s : __builtin_inff();
}

// ---- stage pair p_ (chunks 2p,2p+1) into STG buffer b_ via global_load_lds.
// Fragment-major layout: byte off = b*32768 + k*16384 + pl*8192 + seg*1024
// + lane*16, where seg = t*2 + half; content = F[(2p+k)*64+t*16+(lane&15)]
// [cols (lane>>4)*8 + half*32 .. +8). Wave w issues 4 segs of its (k,pl).
#define ISSUE_PAIR(b_, p_) {                                                  \
    const int k_  = (w >> 2) & 1;                                             \
    const int pl_ = (w >> 1) & 1;                                             \
    const unsigned short* PL_ = pl_ ? Fl : Fh;                                \
    const int segb_ = (w & 1) * 4;                                            \
    _Pragma("unroll")                                                         \
    for (int ii_ = 0; ii_ < 4; ++ii_) {                                       \
        const int seg_ = segb_ + ii_;                                         \
        const int row_ = (p_) * 128 + k_ * 64 + (seg_ >> 1) * 16 + (lane & 15);\
        const int col_ = ((lane >> 4) << 3) + (seg_ & 1) * 32;                \
        const unsigned short* g_ = PL_ + (size_t)row_ * DD + col_;            \
        char* l_ = &STG[(b_) * 32768 + k_ * 16384 + pl_ * 8192 + seg_ * 1024];\
        __builtin_amdgcn_global_load_lds(                                     \
            (const __attribute__((address_space(1))) void*)g_,                \
            (__attribute__((address_space(3))) void*)l_, 16, 0, 0);           \
    }                                                                         \
}

// ---- compute this wave's subtile of pair p_ from STG buffer b_ ----
// defines (assigns) s0..s3, rb4. Two independent MFMA chains.
#define COMPUTE_SUB(b_, p_) {                                                 \
    const int k_ = w >> 2;                                                    \
    const int t_ = w & 3;                                                     \
    const char* sb_ = &STG[(b_) * 32768 + k_ * 16384 + t_ * 2048];            \
    const bf16x8 Ah0 = *(const bf16x8*)(sb_ + lane * 16);                     \
    const bf16x8 Ah1 = *(const bf16x8*)(sb_ + 1024 + lane * 16);              \
    const bf16x8 Al0 = *(const bf16x8*)(sb_ + 8192 + lane * 16);              \
    const bf16x8 Al1 = *(const bf16x8*)(sb_ + 8192 + 1024 + lane * 16);       \
    const int c_ = 2 * (p_) + k_;                                             \
    const f32x4 fnv = *(const f32x4*)(fn + c_ * 64 + t_ * 16 + hgrp * 4);     \
    f32x4 accA = {0.f,0.f,0.f,0.f}, accB = {0.f,0.f,0.f,0.f};                 \
    accA = __builtin_amdgcn_mfma_f32_16x16x32_bf16(Ah0, qh0, accA, 0, 0, 0);  \
    accB = __builtin_amdgcn_mfma_f32_16x16x32_bf16(Ah0, ql0, accB, 0, 0, 0);  \
    accA = __builtin_amdgcn_mfma_f32_16x16x32_bf16(Ah1, qh1, accA, 0, 0, 0);  \
    accB = __builtin_amdgcn_mfma_f32_16x16x32_bf16(Ah1, ql1, accB, 0, 0, 0);  \
    accA = __builtin_amdgcn_mfma_f32_16x16x32_bf16(Al0, qh0, accA, 0, 0, 0);  \
    accB = __builtin_amdgcn_mfma_f32_16x16x32_bf16(Al0, ql0, accB, 0, 0, 0);  \
    accA = __builtin_amdgcn_mfma_f32_16x16x32_bf16(Al1, qh1, accA, 0, 0, 0);  \
    accB = __builtin_amdgcn_mfma_f32_16x16x32_bf16(Al1, ql1, accB, 0, 0, 0);  \
    s0 = fnv[0] - 2.f * (accA[0] + accB[0]);                                  \
    s1 = fnv[1] - 2.f * (accA[1] + accB[1]);                                  \
    s2 = fnv[2] - 2.f * (accA[2] + accB[2]);                                  \
    s3 = fnv[3] - 2.f * (accA[3] + accB[3]);                                  \
    rb4 = c_ * 64 + t_ * 16 + hgrp * 4;                                       \
}

#define GATE_P2 {                                                             \
    const float sv_[4] = {s0, s1, s2, s3};                                    \
    _Pragma("unroll")                                                         \
    for (int j_ = 0; j_ < 4; ++j_) {                                          \
        if (sv_[j_] <= tauR) {                                                \
            const int p_ = atomicAdd(&cnt[q], 1);                             \
            if (p_ < CAP) {                                                   \
                bufd[q * CAP + p_] = sv_[j_];                                 \
                bufi[q * CAP + p_] = (unsigned short)(rb4 + j_);              \
            }                                                                 \
        }                                                                     \
    }                                                                         \
}

__global__ __launch_bounds__(512) void knn_stage(
    const unsigned short* __restrict__ Fh, const unsigned short* __restrict__ Fl,
    const float* __restrict__ fn,
    const unsigned short* __restrict__ Qh, const unsigned short* __restrict__ Ql,
    const float* __restrict__ qn,
    const float* __restrict__ targets, float* __restrict__ out)
{
    __shared__ __align__(16) char STG[65536];        // 2 bufs x pair(2ch x 2pl x 8KB)
    __shared__ __align__(16) char pool[16 * CAP * 6]; // cands: f32 + u16
    __shared__ int cnt_sh[NW * 16];
    __shared__ int cnt[16];

    float*          bufd = (float*)pool;
    unsigned short* bufi = (unsigned short*)(pool + 16 * CAP * 4);

    const int tid  = threadIdx.x;
    const int lane = tid & 63;
    const int w    = tid >> 6;          // 0..7
    const int qbase = blockIdx.x * 16;
    const int q    = lane & 15;
    const int hgrp = lane >> 4;

    if (tid < 16) cnt[tid] = 0;

    // stationary B-operand (Q^T) fragments
    const int qrow = qbase + q;
    const int kof  = hgrp * 8;
    const bf16x8 qh0 = *(const bf16x8*)(Qh + (size_t)qrow * DD + kof);
    const bf16x8 qh1 = *(const bf16x8*)(Qh + (size_t)qrow * DD + kof + 32);
    const bf16x8 ql0 = *(const bf16x8*)(Ql + (size_t)qrow * DD + kof);
    const bf16x8 ql1 = *(const bf16x8*)(Ql + (size_t)qrow * DD + kof + 32);

    // ================= phase 1: staged sample scan -> 64 reg values ========
    float srg[64];
    ISSUE_PAIR(0, 0)
    __syncthreads();
    #pragma unroll
    for (int p = 0; p < NP1; ++p) {
        if (p + 1 < NP1) { ISSUE_PAIR((p + 1) & 1, p + 1) }
        float s0, s1, s2, s3; int rb4;
        COMPUTE_SUB(p & 1, p)
        (void)rb4;
        srg[p * 4 + 0] = s0; srg[p * 4 + 1] = s1;
        srg[p * 4 + 2] = s2; srg[p * 4 + 3] = s3;
        __syncthreads();
    }

    // ---- tau: 16-bit key bit-descent over the 2048-row sample ----
    unsigned lo16 = 0;
    #pragma unroll 1
    for (int bit = 15; bit >= 0; --bit) {
        const unsigned trial = lo16 | (1u << bit);
        const float bnd = dec32(trial << 16);    // key(v)<trial  <=>  v<bnd
        int c = 0;
        #pragma unroll
        for (int u = 0; u < 64; ++u) c += (srg[u] < bnd) ? 1 : 0;
        c += __shfl_xor(c, 16);
        c += __shfl_xor(c, 32);
        if (lane < 16) cnt_sh[w * 16 + lane] = c;
        __syncthreads();
        int tot = 0;
        #pragma unroll
        for (int ww = 0; ww < NW; ++ww) tot += cnt_sh[ww * 16 + q];
        if (tot < KK) lo16 = trial;
        __syncthreads();
    }
    const float tauR = (lo16 >= 0xFFFFu) ? __builtin_inff()
                                         : dec32((lo16 + 1u) << 16);

    // ================= phase 2: staged full scan, gated append =============
    ISSUE_PAIR(0, 0)
    __syncthreads();
    for (int p = 0; p < NP2; ++p) {
        if (p + 1 < NP2) { ISSUE_PAIR((p + 1) & 1, p + 1) }
        float s0, s1, s2, s3; int rb4;
        COMPUTE_SUB(p & 1, p)
        GATE_P2
        __syncthreads();
    }

    // ================= phase 3: exact rank + weighted sum ==================
    #pragma unroll
    for (int e = 0; e < 2; ++e) {
        const int q3 = w * 2 + e;
        const int n  = min(cnt[q3], CAP);
        const float qnv = qn[qbase + q3];

        float    ms[12]; unsigned kk[12]; unsigned short miu[12];
        #pragma unroll
        for (int u = 0; u < 12; ++u) {
            const int j = lane + u * 64;
            const bool v = (j < n);
            ms[u]  = v ? bufd[q3 * CAP + j] : __builtin_inff();
            miu[u] = v ? bufi[q3 * CAP + j] : (unsigned short)0xFFFFu;
            kk[u]  = enc32(ms[u]);
        }
        unsigned lo = 0;
        for (int bit = 31; bit >= 0; --bit) {
            const unsigned trial = lo | (1u << bit);
            int c = 0;
            #pragma unroll
            for (int u = 0; u < 12; ++u) c += (kk[u] < trial);
            #pragma unroll
            for (int o = 32; o >= 1; o >>= 1) c += __shfl_xor(c, o);
            if (c < KK) lo = trial;
        }
        int c0 = 0, tcnt = 0;
        #pragma unroll
        for (int u = 0; u < 12; ++u) { c0 += (kk[u] < lo); tcnt += (kk[u] == lo); }
        #pragma unroll
        for (int o = 32; o >= 1; o >>= 1) {
            c0 += __shfl_xor(c0, o); tcnt += __shfl_xor(tcnt, o);
        }
        const int kprime = KK - c0;
        unsigned ilo = 0xFFFFu;
        if (tcnt != kprime) {
            ilo = 0;
            for (int bit = 15; bit >= 0; --bit) {
                const unsigned trial = ilo | (1u << bit);
                int c = 0;
                #pragma unroll
                for (int u = 0; u < 12; ++u)
                    c += ((kk[u] == lo) && ((unsigned)miu[u] < trial));
                #pragma unroll
                for (int o = 32; o >= 1; o >>= 1) c += __shfl_xor(c, o);
                if (c < kprime) ilo = trial;
            }
        }
        float nume = 0.f, deno = 0.f;
        #pragma unroll
        for (int u = 0; u < 12; ++u) {
            const bool inc = (kk[u] < lo) ||
                             ((kk[u] == lo) && ((unsigned)miu[u] <= ilo));
            if (inc) {
                const float d2 = fmaxf(qnv + ms[u], 0.f);
                const float wv = 1.f / (d2 + 1e-4f);
                nume = fmaf(wv, targets[miu[u]], nume);
                deno += wv;
            }
        }
        #pragma unroll
        for (int o = 32; o >= 1; o >>= 1) {
            nume += __shfl_xor(nume, o);
            deno += __shfl_xor(deno, o);
        }
        if (lane == 0) out[qbase + q3] = nume / fmaxf(deno, 1e-9f);
    }
}

// ---------------- fallback: round-1 exact fp32 vector kernel ----------------
#define BQ 32
#define WQ 8
__global__ __launch_bounds__(256) void hp_knn_kernel(
    const float* __restrict__ points, const float* __restrict__ features,
    const float* __restrict__ targets, float* __restrict__ out)
{
    __shared__ __align__(16) float Qs[BQ][DD];
    __shared__ float qn_s[BQ];
    __shared__ float topd[BQ][KK];
    __shared__ int   topi[BQ][KK];
    const int tid = threadIdx.x, lane = tid & 63, wv = tid >> 6, qb = wv * WQ;
    {
        const float4* src = (const float4*)(points + (size_t)blockIdx.x * BQ * DD);
        float4* dst = (float4*)&Qs[0][0];
        #pragma unroll
        for (int i = 0; i < (BQ * DD / 4) / 256; ++i) dst[tid + i * 256] = src[tid + i * 256];
    }
    for (int i = tid; i < BQ * KK; i += 256) { (&topd[0][0])[i] = __builtin_inff(); (&topi[0][0])[i] = 0; }
    __syncthreads();
    if (tid < BQ) {
        float s = 0.f;
        #pragma unroll
        for (int d = 0; d < DD; ++d) s = fmaf(Qs[tid][d], Qs[tid][d], s);
        qn_s[tid] = s;
    }
    __syncthreads();
    for (int c = 0; c < (MM + 63) / 64; ++c) {
        const int m = c * 64 + lane, mc = (m < MM) ? m : (MM - 1);
        float f[DD];
        const float4* fr = (const float4*)(features + (size_t)mc * DD);
        #pragma unroll
        for (int b = 0; b < DD / 4; ++b) { float4 v = fr[b]; f[4*b]=v.x; f[4*b+1]=v.y; f[4*b+2]=v.z; f[4*b+3]=v.w; }
        float fnv = 0.f;
        #pragma unroll
        for (int d = 0; d < DD; ++d) fnv = fmaf(f[d], f[d], fnv);
        float d2v[WQ];
        #pragma unroll
        for (int qi = 0; qi < WQ; ++qi) {
            const float4* qr = (const float4*)&Qs[qb + qi][0];
            float a0=0,a1=0,a2=0,a3=0;
            #pragma unroll
            for (int b = 0; b < DD / 4; ++b) {
                float4 q4 = qr[b];
                a0 = fmaf(q4.x, f[4*b], a0); a1 = fmaf(q4.y, f[4*b+1], a1);
                a2 = fmaf(q4.z, f[4*b+2], a2); a3 = fmaf(q4.w, f[4*b+3], a3);
            }
            float d2 = fmaxf(qn_s[qb+qi] + fnv - 2.f*((a0+a1)+(a2+a3)), 0.f);
            d2v[qi] = (m < MM) ? d2 : __builtin_inff();
        }
        #pragma unroll
        for (int qi = 0; qi < WQ; ++qi) {
            const int q = qb + qi;
            unsigned long long ball = __ballot(d2v[qi] < topd[q][KK-1]);
            while (ball) {
                const int j = __builtin_ctzll(ball); ball &= ball - 1;
                const float dval = __shfl(d2v[qi], j); const int mval = c * 64 + j;
                if (lane < KK) {
                    const float cur = topd[q][lane];
                    if (cur > dval) {
                        const float pd = (lane > 0) ? topd[q][lane-1] : -1.f;
                        const int   pi = (lane > 0) ? topi[q][lane-1] : 0;
                        const bool tp = (pd > dval);
                        topd[q][lane] = tp ? pd : dval; topi[q][lane] = tp ? pi : mval;
                    }
                }
            }
        }
    }
    #pragma unroll
    for (int qi = 0; qi < WQ; ++qi) {
        const int q = qb + qi;
        float wsum = 0.f, wt = 0.f;
        if (lane < KK) {
            const float ww = 1.f / (topd[q][lane] + 1e-4f);
            wsum = ww; wt = ww * targets[topi[q][lane]];
        }
        #pragma unroll
        for (int o = 32; o >= 1; o >>= 1) { wsum += __shfl_xor(wsum, o); wt += __shfl_xor(wt, o); }
        if (lane == 0) out[(size_t)blockIdx.x * BQ + q] = wt / fmaxf(wsum, 1e-9f);
    }
}

extern "C" void kernel_launch(void* const* d_in, const int* in_sizes, int n_in,
                              void* d_out, int out_size, void* d_ws, size_t ws_size,
                              hipStream_t stream) {
    const float* points   = (const float*)d_in[0];
    const float* features = (const float*)d_in[1];
    const float* targets  = (const float*)d_in[2];
    float* out = (float*)d_out;

    if (ws_size < (size_t)WS_REQ) {
        hp_knn_kernel<<<dim3(NQ / BQ), dim3(256), 0, stream>>>(points, features, targets, out);
        return;
    }
    char* ws = (char*)d_ws;
    unsigned short* Fh = (unsigned short*)(ws + OFF_FH);
    unsigned short* Fl = (unsigned short*)(ws + OFF_FL);
    float*          fn = (float*)(ws + OFF_FN);
    unsigned short* Qh = (unsigned short*)(ws + OFF_QH);
    unsigned short* Ql = (unsigned short*)(ws + OFF_QL);
    float*          qnp= (float*)(ws + OFF_QN);

    prep_split<<<dim3(MPAD * DD / 256), dim3(256), 0, stream>>>(features, Fh, Fl, fn, MM);
    prep_split<<<dim3(NQ * DD / 256),  dim3(256), 0, stream>>>(points,   Qh, Ql, qnp, NQ);
    knn_stage<<<dim3(NQ / 16), dim3(512), 0, stream>>>(Fh, Fl, fn, Qh, Ql, qnp, targets, out);
}

// Round 9
// 507.561 us; speedup vs baseline: 2.4566x; 2.4566x over previous
//
#include <hip/hip_runtime.h>
#include <hip/hip_bf16.h>
#include <math.h>

// Split-bf16 MFMA exact-KNN (K=32) + inverse-squared-distance weighting.
// points:[16384,64] features:[20000,64] targets:[20000] -> out:[16384]
//
// Round 9: filter-then-rank (R6) at 32 q/block (512 blocks) for 2x
// arithmetic intensity on the feature stream. Per wave: 2 stationary
// Q-fragment sets; 16 MFMA (4 indep chains) per 5-load subtile. Sample
// keys for both q-groups in LDS (u16, stride 2056); tau via bit-descent;
// candidate buffers (32 x 576) overlay the sample pool. Phase 2 has no
// LDS reads and no barriers (register tau + atomic append).

#define NQ   16384
#define MM   20000
#define DD   64
#define KK   32
#define MPAD 20032
#define NCH  (MPAD / 64)   // 313
#define NW   8
#define QB   32            // queries per block
#define CAP  576
#define SMPN 2048          // sample rows = chunks 0..31
#define SMPS 2056          // padded u16 stride

typedef __attribute__((ext_vector_type(8))) short bf16x8;
typedef __attribute__((ext_vector_type(4))) float f32x4;

// ---- workspace layout (bytes) ----
#define OFF_FH 0
#define SZ_FP  (MPAD * DD * 2)
#define OFF_FL (OFF_FH + SZ_FP)
#define OFF_FN (OFF_FL + SZ_FP)
#define SZ_FN  (MPAD * 4)
#define OFF_QH (OFF_FN + SZ_FN)
#define SZ_QP  (NQ * DD * 2)
#define OFF_QL (OFF_QH + SZ_QP)
#define OFF_QN (OFF_QL + SZ_QP)
#define SZ_QN  (NQ * 4)
#define WS_REQ (OFF_QN + SZ_QN)

__device__ __forceinline__ unsigned int bf16_rne(float x) {
    unsigned int xb = __float_as_uint(x);
    return (xb + 0x7fffu + ((xb >> 16) & 1u)) & 0xffff0000u;
}
__device__ __forceinline__ unsigned enc32(float f) {
    unsigned b = __float_as_uint(f);
    return (b & 0x80000000u) ? ~b : (b | 0x80000000u);
}
__device__ __forceinline__ float dec32(unsigned k) {
    unsigned b = (k & 0x80000000u) ? (k & 0x7FFFFFFFu) : ~k;
    return __uint_as_float(b);
}

__global__ void prep_split(const float* __restrict__ src,
                           unsigned short* __restrict__ ph,
                           unsigned short* __restrict__ pl,
                           float* __restrict__ nrm, int nrows_real) {
    const int e = blockIdx.x * 256 + threadIdx.x;
    const int m = e >> 6;
    const int lane = threadIdx.x & 63;
    const bool real = (m < nrows_real);
    float x = real ? src[e] : 0.f;
    unsigned int hb = bf16_rne(x);
    float xh = __uint_as_float(hb);
    unsigned int lb = bf16_rne(x - xh);
    ph[e] = (unsigned short)(hb >> 16);
    pl[e] = (unsigned short)(lb >> 16);
    float s = x * x;
    #pragma unroll
    for (int o = 32; o >= 1; o >>= 1) s += __shfl_xor(s, o);
    if (lane == 0) nrm[m] = real ? s : __builtin_inff();
}

// one subtile: 5 loads, 16 MFMA (4 independent chains), both q-groups.
// defines sA0..sA3 (group 0), sB0..sB3 (group 1), rb4.
#define SUBTILE2(c_, t_)                                                       \
    const int frow = (c_) * 64 + (t_) * 16 + q;                                \
    const unsigned short* phh = Fh + (size_t)frow * DD + kof;                  \
    const unsigned short* pll = Fl + (size_t)frow * DD + kof;                  \
    const bf16x8 Ah0 = *(const bf16x8*)(phh);                                  \
    const bf16x8 Ah1 = *(const bf16x8*)(phh + 32);                             \
    const bf16x8 Al0 = *(const bf16x8*)(pll);                                  \
    const bf16x8 Al1 = *(const bf16x8*)(pll + 32);                             \
    const f32x4  fnv = *(const f32x4*)(fn + (c_) * 64 + (t_) * 16 + hgrp * 4); \
    f32x4 a0 = {0.f,0.f,0.f,0.f}, b0 = {0.f,0.f,0.f,0.f};                      \
    f32x4 a1 = {0.f,0.f,0.f,0.f}, b1 = {0.f,0.f,0.f,0.f};                      \
    a0 = __builtin_amdgcn_mfma_f32_16x16x32_bf16(Ah0, qh0A, a0, 0, 0, 0);      \
    b0 = __builtin_amdgcn_mfma_f32_16x16x32_bf16(Ah0, ql0A, b0, 0, 0, 0);      \
    a1 = __builtin_amdgcn_mfma_f32_16x16x32_bf16(Ah0, qh0B, a1, 0, 0, 0);      \
    b1 = __builtin_amdgcn_mfma_f32_16x16x32_bf16(Ah0, ql0B, b1, 0, 0, 0);      \
    a0 = __builtin_amdgcn_mfma_f32_16x16x32_bf16(Ah1, qh1A, a0, 0, 0, 0);      \
    b0 = __builtin_amdgcn_mfma_f32_16x16x32_bf16(Ah1, ql1A, b0, 0, 0, 0);      \
    a1 = __builtin_amdgcn_mfma_f32_16x16x32_bf16(Ah1, qh1B, a1, 0, 0, 0);      \
    b1 = __builtin_amdgcn_mfma_f32_16x16x32_bf16(Ah1, ql1B, b1, 0, 0, 0);      \
    a0 = __builtin_amdgcn_mfma_f32_16x16x32_bf16(Al0, qh0A, a0, 0, 0, 0);      \
    b0 = __builtin_amdgcn_mfma_f32_16x16x32_bf16(Al0, ql0A, b0, 0, 0, 0);      \
    a1 = __builtin_amdgcn_mfma_f32_16x16x32_bf16(Al0, qh0B, a1, 0, 0, 0);      \
    b1 = __builtin_amdgcn_mfma_f32_16x16x32_bf16(Al0, ql0B, b1, 0, 0, 0);      \
    a0 = __builtin_amdgcn_mfma_f32_16x16x32_bf16(Al1, qh1A, a0, 0, 0, 0);      \
    b0 = __builtin_amdgcn_mfma_f32_16x16x32_bf16(Al1, ql1A, b0, 0, 0, 0);      \
    a1 = __builtin_amdgcn_mfma_f32_16x16x32_bf16(Al1, qh1B, a1, 0, 0, 0);      \
    b1 = __builtin_amdgcn_mfma_f32_16x16x32_bf16(Al1, ql1B, b1, 0, 0, 0);      \
    const float sA0 = fnv[0] - 2.f * (a0[0] + b0[0]);                          \
    const float sA1 = fnv[1] - 2.f * (a0[1] + b0[1]);                          \
    const float sA2 = fnv[2] - 2.f * (a0[2] + b0[2]);                          \
    const float sA3 = fnv[3] - 2.f * (a0[3] + b0[3]);                          \
    const float sB0 = fnv[0] - 2.f * (a1[0] + b1[0]);                          \
    const float sB1 = fnv[1] - 2.f * (a1[1] + b1[1]);                          \
    const float sB2 = fnv[2] - 2.f * (a1[2] + b1[2]);                          \
    const float sB3 = fnv[3] - 2.f * (a1[3] + b1[3]);                          \
    const int rb4 = (c_) * 64 + (t_) * 16 + hgrp * 4;

#define GATE2(qq_, tau_, s0_, s1_, s2_, s3_) {                                 \
    const float sv_[4] = {s0_, s1_, s2_, s3_};                                 \
    _Pragma("unroll")                                                          \
    for (int j_ = 0; j_ < 4; ++j_) {                                           \
        if (sv_[j_] <= (tau_)) {                                               \
            const int p_ = atomicAdd(&cnt[qq_], 1);                            \
            if (p_ < CAP) {                                                    \
                bufd[(qq_) * CAP + p_] = sv_[j_];                              \
                bufi[(qq_) * CAP + p_] = (unsigned short)(rb4 + j_);           \
            }                                                                  \
        }                                                                      \
    }                                                                          \
}

__global__ __launch_bounds__(512) void knn_filter32(
    const unsigned short* __restrict__ Fh, const unsigned short* __restrict__ Fl,
    const float* __restrict__ fn,
    const unsigned short* __restrict__ Qh, const unsigned short* __restrict__ Ql,
    const float* __restrict__ qn,
    const float* __restrict__ targets, float* __restrict__ out)
{
    // pool: phase1 = smp u16[32][SMPS] (131.6 KB); phase2/3 = bufd f32[32][CAP]
    // (73.7 KB) + bufi u16[32][CAP] (36.9 KB).
    __shared__ __align__(16) unsigned char pool[QB * SMPS * 2];
    __shared__ float tau_f[QB];
    __shared__ int   cnt[QB];

    unsigned short* smp  = (unsigned short*)pool;
    float*          bufd = (float*)pool;
    unsigned short* bufi = (unsigned short*)(pool + QB * CAP * 4);

    const int tid  = threadIdx.x;
    const int lane = tid & 63;
    const int w    = tid >> 6;          // 0..7
    const int qbase = blockIdx.x * QB;
    const int q    = lane & 15;
    const int hgrp = lane >> 4;
    const int kof  = hgrp * 8;

    if (tid < QB) cnt[tid] = 0;

    // stationary B-operand (Q^T) fragments, two query groups
    const int qrow0 = qbase + q;
    const int qrow1 = qbase + 16 + q;
    const bf16x8 qh0A = *(const bf16x8*)(Qh + (size_t)qrow0 * DD + kof);
    const bf16x8 qh1A = *(const bf16x8*)(Qh + (size_t)qrow0 * DD + kof + 32);
    const bf16x8 ql0A = *(const bf16x8*)(Ql + (size_t)qrow0 * DD + kof);
    const bf16x8 ql1A = *(const bf16x8*)(Ql + (size_t)qrow0 * DD + kof + 32);
    const bf16x8 qh0B = *(const bf16x8*)(Qh + (size_t)qrow1 * DD + kof);
    const bf16x8 qh1B = *(const bf16x8*)(Qh + (size_t)qrow1 * DD + kof + 32);
    const bf16x8 ql0B = *(const bf16x8*)(Ql + (size_t)qrow1 * DD + kof);
    const bf16x8 ql1B = *(const bf16x8*)(Ql + (size_t)qrow1 * DD + kof + 32);

    // ============ phase 1: sample scan (chunks 0..31) -> u16 keys ==========
    #pragma unroll
    for (int cc = 0; cc < 4; ++cc) {
        const int chunk = w * 4 + cc;
        #pragma unroll
        for (int t = 0; t < 4; ++t) {
            SUBTILE2(chunk, t)
            ushort4 kA, kB;
            kA.x = (unsigned short)(enc32(sA0) >> 16);
            kA.y = (unsigned short)(enc32(sA1) >> 16);
            kA.z = (unsigned short)(enc32(sA2) >> 16);
            kA.w = (unsigned short)(enc32(sA3) >> 16);
            kB.x = (unsigned short)(enc32(sB0) >> 16);
            kB.y = (unsigned short)(enc32(sB1) >> 16);
            kB.z = (unsigned short)(enc32(sB2) >> 16);
            kB.w = (unsigned short)(enc32(sB3) >> 16);
            *(ushort4*)&smp[q * SMPS + rb4]        = kA;
            *(ushort4*)&smp[(16 + q) * SMPS + rb4] = kB;
        }
    }
    __syncthreads();

    // ---- tau per query: 16-bit count-select; wave w owns queries w*4..w*4+3
    #pragma unroll
    for (int e = 0; e < 4; ++e) {
        const int qq = w * 4 + e;
        unsigned short vv[32];
        #pragma unroll
        for (int u = 0; u < 32; ++u) vv[u] = smp[qq * SMPS + lane + u * 64];
        unsigned lo = 0;
        #pragma unroll
        for (int bit = 15; bit >= 0; --bit) {
            const unsigned trial = lo | (1u << bit);
            int c = 0;
            #pragma unroll
            for (int u = 0; u < 32; ++u) c += (vv[u] < trial);
            #pragma unroll
            for (int o = 32; o >= 1; o >>= 1) c += __shfl_xor(c, o);
            if (c < KK) lo = trial;
        }
        const float tf = (lo >= 0xFFFFu) ? __builtin_inff()
                                         : dec32((lo + 1u) << 16);
        if (lane == 0) tau_f[qq] = tf;
    }
    __syncthreads();   // smp dead; candidate buffers take over the pool

    // ============ phase 2: full scan, register-tau gated append ============
    const float tauR0 = tau_f[q];
    const float tauR1 = tau_f[16 + q];
    for (int c = w; c < NCH; c += NW) {
        #pragma unroll
        for (int t = 0; t < 4; ++t) {
            SUBTILE2(c, t)
            GATE2(q,      tauR0, sA0, sA1, sA2, sA3)
            GATE2(16 + q, tauR1, sB0, sB1, sB2, sB3)
        }
    }
    __syncthreads();

    // ============ phase 3: exact rank + weighted sum (4 q per wave) ========
    #pragma unroll
    for (int e = 0; e < 4; ++e) {
        const int q3 = w * 4 + e;
        const int n  = min(cnt[q3], CAP);
        const float qnv = qn[qbase + q3];

        float    ms[9]; unsigned kk[9]; unsigned short miu[9];
        #pragma unroll
        for (int u = 0; u < 9; ++u) {
            const int j = lane + u * 64;
            const bool v = (j < n);
            ms[u]  = v ? bufd[q3 * CAP + j] : __builtin_inff();
            miu[u] = v ? bufi[q3 * CAP + j] : (unsigned short)0xFFFFu;
            kk[u]  = enc32(ms[u]);
        }
        unsigned lo = 0;
        for (int bit = 31; bit >= 0; --bit) {
            const unsigned trial = lo | (1u << bit);
            int c = 0;
            #pragma unroll
            for (int u = 0; u < 9; ++u) c += (kk[u] < trial);
            #pragma unroll
            for (int o = 32; o >= 1; o >>= 1) c += __shfl_xor(c, o);
            if (c < KK) lo = trial;
        }
        int c0 = 0, tcnt = 0;
        #pragma unroll
        for (int u = 0; u < 9; ++u) { c0 += (kk[u] < lo); tcnt += (kk[u] == lo); }
        #pragma unroll
        for (int o = 32; o >= 1; o >>= 1) {
            c0 += __shfl_xor(c0, o); tcnt += __shfl_xor(tcnt, o);
        }
        const int kprime = KK - c0;
        unsigned ilo = 0xFFFFu;
        if (tcnt != kprime) {
            ilo = 0;
            for (int bit = 15; bit >= 0; --bit) {
                const unsigned trial = ilo | (1u << bit);
                int c = 0;
                #pragma unroll
                for (int u = 0; u < 9; ++u)
                    c += ((kk[u] == lo) && ((unsigned)miu[u] < trial));
                #pragma unroll
                for (int o = 32; o >= 1; o >>= 1) c += __shfl_xor(c, o);
                if (c < kprime) ilo = trial;
            }
        }
        float nume = 0.f, deno = 0.f;
        #pragma unroll
        for (int u = 0; u < 9; ++u) {
            const bool inc = (kk[u] < lo) ||
                             ((kk[u] == lo) && ((unsigned)miu[u] <= ilo));
            if (inc) {
                const float d2 = fmaxf(qnv + ms[u], 0.f);
                const float wv = 1.f / (d2 + 1e-4f);
                nume = fmaf(wv, targets[miu[u]], nume);
                deno += wv;
            }
        }
        #pragma unroll
        for (int o = 32; o >= 1; o >>= 1) {
            nume += __shfl_xor(nume, o);
            deno += __shfl_xor(deno, o);
        }
        if (lane == 0) out[qbase + q3] = nume / fmaxf(deno, 1e-9f);
    }
}

// ---------------- fallback: round-1 exact fp32 vector kernel ----------------
#define BQ 32
#define WQ 8
__global__ __launch_bounds__(256) void hp_knn_kernel(
    const float* __restrict__ points, const float* __restrict__ features,
    const float* __restrict__ targets, float* __restrict__ out)
{
    __shared__ __align__(16) float Qs[BQ][DD];
    __shared__ float qn_s[BQ];
    __shared__ float topd[BQ][KK];
    __shared__ int   topi[BQ][KK];
    const int tid = threadIdx.x, lane = tid & 63, wv = tid >> 6, qb = wv * WQ;
    {
        const float4* src = (const float4*)(points + (size_t)blockIdx.x * BQ * DD);
        float4* dst = (float4*)&Qs[0][0];
        #pragma unroll
        for (int i = 0; i < (BQ * DD / 4) / 256; ++i) dst[tid + i * 256] = src[tid + i * 256];
    }
    for (int i = tid; i < BQ * KK; i += 256) { (&topd[0][0])[i] = __builtin_inff(); (&topi[0][0])[i] = 0; }
    __syncthreads();
    if (tid < BQ) {
        float s = 0.f;
        #pragma unroll
        for (int d = 0; d < DD; ++d) s = fmaf(Qs[tid][d], Qs[tid][d], s);
        qn_s[tid] = s;
    }
    __syncthreads();
    for (int c = 0; c < (MM + 63) / 64; ++c) {
        const int m = c * 64 + lane, mc = (m < MM) ? m : (MM - 1);
        float f[DD];
        const float4* fr = (const float4*)(features + (size_t)mc * DD);
        #pragma unroll
        for (int b = 0; b < DD / 4; ++b) { float4 v = fr[b]; f[4*b]=v.x; f[4*b+1]=v.y; f[4*b+2]=v.z; f[4*b+3]=v.w; }
        float fnv = 0.f;
        #pragma unroll
        for (int d = 0; d < DD; ++d) fnv = fmaf(f[d], f[d], fnv);
        float d2v[WQ];
        #pragma unroll
        for (int qi = 0; qi < WQ; ++qi) {
            const float4* qr = (const float4*)&Qs[qb + qi][0];
            float a0=0,a1=0,a2=0,a3=0;
            #pragma unroll
            for (int b = 0; b < DD / 4; ++b) {
                float4 q4 = qr[b];
                a0 = fmaf(q4.x, f[4*b], a0); a1 = fmaf(q4.y, f[4*b+1], a1);
                a2 = fmaf(q4.z, f[4*b+2], a2); a3 = fmaf(q4.w, f[4*b+3], a3);
            }
            float d2 = fmaxf(qn_s[qb+qi] + fnv - 2.f*((a0+a1)+(a2+a3)), 0.f);
            d2v[qi] = (m < MM) ? d2 : __builtin_inff();
        }
        #pragma unroll
        for (int qi = 0; qi < WQ; ++qi) {
            const int q = qb + qi;
            unsigned long long ball = __ballot(d2v[qi] < topd[q][KK-1]);
            while (ball) {
                const int j = __builtin_ctzll(ball); ball &= ball - 1;
                const float dval = __shfl(d2v[qi], j); const int mval = c * 64 + j;
                if (lane < KK) {
                    const float cur = topd[q][lane];
                    if (cur > dval) {
                        const float pd = (lane > 0) ? topd[q][lane-1] : -1.f;
                        const int   pi = (lane > 0) ? topi[q][lane-1] : 0;
                        const bool tp = (pd > dval);
                        topd[q][lane] = tp ? pd : dval; topi[q][lane] = tp ? pi : mval;
                    }
                }
            }
        }
    }
    #pragma unroll
    for (int qi = 0; qi < WQ; ++qi) {
        const int q = qb + qi;
        float wsum = 0.f, wt = 0.f;
        if (lane < KK) {
            const float ww = 1.f / (topd[q][lane] + 1e-4f);
            wsum = ww; wt = ww * targets[topi[q][lane]];
        }
        #pragma unroll
        for (int o = 32; o >= 1; o >>= 1) { wsum += __shfl_xor(wsum, o); wt += __shfl_xor(wt, o); }
        if (lane == 0) out[(size_t)blockIdx.x * BQ + q] = wt / fmaxf(wsum, 1e-9f);
    }
}

extern "C" void kernel_launch(void* const* d_in, const int* in_sizes, int n_in,
                              void* d_out, int out_size, void* d_ws, size_t ws_size,
                              hipStream_t stream) {
    const float* points   = (const float*)d_in[0];
    const float* features = (const float*)d_in[1];
    const float* targets  = (const float*)d_in[2];
    float* out = (float*)d_out;

    if (ws_size < (size_t)WS_REQ) {
        hp_knn_kernel<<<dim3(NQ / BQ), dim3(256), 0, stream>>>(points, features, targets, out);
        return;
    }
    char* ws = (char*)d_ws;
    unsigned short* Fh = (unsigned short*)(ws + OFF_FH);
    unsigned short* Fl = (unsigned short*)(ws + OFF_FL);
    float*          fn = (float*)(ws + OFF_FN);
    unsigned short* Qh = (unsigned short*)(ws + OFF_QH);
    unsigned short* Ql = (unsigned short*)(ws + OFF_QL);
    float*          qnp= (float*)(ws + OFF_QN);

    prep_split<<<dim3(MPAD * DD / 256), dim3(256), 0, stream>>>(features, Fh, Fl, fn, MM);
    prep_split<<<dim3(NQ * DD / 256),  dim3(256), 0, stream>>>(points,   Qh, Ql, qnp, NQ);
    knn_filter32<<<dim3(NQ / QB), dim3(512), 0, stream>>>(Fh, Fl, fn, Qh, Ql, qnp, targets, out);
}

// Round 10
// 429.500 us; speedup vs baseline: 2.9031x; 1.1817x over previous
//
#include <hip/hip_runtime.h>
#include <hip/hip_bf16.h>
#include <math.h>

// Split-bf16 MFMA exact-KNN (K=32) + inverse-squared-distance weighting.
// points:[16384,64] features:[20000,64] targets:[20000] -> out:[16384]
//
// Round 10: R9 structure (filter-then-rank, 32 q/block, 2x Q-groups,
// 16 MFMA / 5-load subtile) at 1024 threads/block (16 waves). LDS pool
// forces 1 block/CU regardless, so a double-size block doubles waves/SIMD
// (2->4) with identical traffic and numerics. m-stride 16; sample wave
// handles 2 chunks; tau + rank phases handle 2 q/wave.

#define NQ   16384
#define MM   20000
#define DD   64
#define KK   32
#define MPAD 20032
#define NCH  (MPAD / 64)   // 313
#define NW   16            // waves per block
#define QB   32            // queries per block
#define CAP  576
#define SMPN 2048          // sample rows = chunks 0..31
#define SMPS 2056          // padded u16 stride

typedef __attribute__((ext_vector_type(8))) short bf16x8;
typedef __attribute__((ext_vector_type(4))) float f32x4;

// ---- workspace layout (bytes) ----
#define OFF_FH 0
#define SZ_FP  (MPAD * DD * 2)
#define OFF_FL (OFF_FH + SZ_FP)
#define OFF_FN (OFF_FL + SZ_FP)
#define SZ_FN  (MPAD * 4)
#define OFF_QH (OFF_FN + SZ_FN)
#define SZ_QP  (NQ * DD * 2)
#define OFF_QL (OFF_QH + SZ_QP)
#define OFF_QN (OFF_QL + SZ_QP)
#define SZ_QN  (NQ * 4)
#define WS_REQ (OFF_QN + SZ_QN)

__device__ __forceinline__ unsigned int bf16_rne(float x) {
    unsigned int xb = __float_as_uint(x);
    return (xb + 0x7fffu + ((xb >> 16) & 1u)) & 0xffff0000u;
}
__device__ __forceinline__ unsigned enc32(float f) {
    unsigned b = __float_as_uint(f);
    return (b & 0x80000000u) ? ~b : (b | 0x80000000u);
}
__device__ __forceinline__ float dec32(unsigned k) {
    unsigned b = (k & 0x80000000u) ? (k & 0x7FFFFFFFu) : ~k;
    return __uint_as_float(b);
}

__global__ void prep_split(const float* __restrict__ src,
                           unsigned short* __restrict__ ph,
                           unsigned short* __restrict__ pl,
                           float* __restrict__ nrm, int nrows_real) {
    const int e = blockIdx.x * 256 + threadIdx.x;
    const int m = e >> 6;
    const int lane = threadIdx.x & 63;
    const bool real = (m < nrows_real);
    float x = real ? src[e] : 0.f;
    unsigned int hb = bf16_rne(x);
    float xh = __uint_as_float(hb);
    unsigned int lb = bf16_rne(x - xh);
    ph[e] = (unsigned short)(hb >> 16);
    pl[e] = (unsigned short)(lb >> 16);
    float s = x * x;
    #pragma unroll
    for (int o = 32; o >= 1; o >>= 1) s += __shfl_xor(s, o);
    if (lane == 0) nrm[m] = real ? s : __builtin_inff();
}

// one subtile: 5 loads, 16 MFMA (4 independent chains), both q-groups.
// defines sA0..sA3 (group 0), sB0..sB3 (group 1), rb4.
#define SUBTILE2(c_, t_)                                                       \
    const int frow = (c_) * 64 + (t_) * 16 + q;                                \
    const unsigned short* phh = Fh + (size_t)frow * DD + kof;                  \
    const unsigned short* pll = Fl + (size_t)frow * DD + kof;                  \
    const bf16x8 Ah0 = *(const bf16x8*)(phh);                                  \
    const bf16x8 Ah1 = *(const bf16x8*)(phh + 32);                             \
    const bf16x8 Al0 = *(const bf16x8*)(pll);                                  \
    const bf16x8 Al1 = *(const bf16x8*)(pll + 32);                             \
    const f32x4  fnv = *(const f32x4*)(fn + (c_) * 64 + (t_) * 16 + hgrp * 4); \
    f32x4 a0 = {0.f,0.f,0.f,0.f}, b0 = {0.f,0.f,0.f,0.f};                      \
    f32x4 a1 = {0.f,0.f,0.f,0.f}, b1 = {0.f,0.f,0.f,0.f};                      \
    a0 = __builtin_amdgcn_mfma_f32_16x16x32_bf16(Ah0, qh0A, a0, 0, 0, 0);      \
    b0 = __builtin_amdgcn_mfma_f32_16x16x32_bf16(Ah0, ql0A, b0, 0, 0, 0);      \
    a1 = __builtin_amdgcn_mfma_f32_16x16x32_bf16(Ah0, qh0B, a1, 0, 0, 0);      \
    b1 = __builtin_amdgcn_mfma_f32_16x16x32_bf16(Ah0, ql0B, b1, 0, 0, 0);      \
    a0 = __builtin_amdgcn_mfma_f32_16x16x32_bf16(Ah1, qh1A, a0, 0, 0, 0);      \
    b0 = __builtin_amdgcn_mfma_f32_16x16x32_bf16(Ah1, ql1A, b0, 0, 0, 0);      \
    a1 = __builtin_amdgcn_mfma_f32_16x16x32_bf16(Ah1, qh1B, a1, 0, 0, 0);      \
    b1 = __builtin_amdgcn_mfma_f32_16x16x32_bf16(Ah1, ql1B, b1, 0, 0, 0);      \
    a0 = __builtin_amdgcn_mfma_f32_16x16x32_bf16(Al0, qh0A, a0, 0, 0, 0);      \
    b0 = __builtin_amdgcn_mfma_f32_16x16x32_bf16(Al0, ql0A, b0, 0, 0, 0);      \
    a1 = __builtin_amdgcn_mfma_f32_16x16x32_bf16(Al0, qh0B, a1, 0, 0, 0);      \
    b1 = __builtin_amdgcn_mfma_f32_16x16x32_bf16(Al0, ql0B, b1, 0, 0, 0);      \
    a0 = __builtin_amdgcn_mfma_f32_16x16x32_bf16(Al1, qh1A, a0, 0, 0, 0);      \
    b0 = __builtin_amdgcn_mfma_f32_16x16x32_bf16(Al1, ql1A, b0, 0, 0, 0);      \
    a1 = __builtin_amdgcn_mfma_f32_16x16x32_bf16(Al1, qh1B, a1, 0, 0, 0);      \
    b1 = __builtin_amdgcn_mfma_f32_16x16x32_bf16(Al1, ql1B, b1, 0, 0, 0);      \
    const float sA0 = fnv[0] - 2.f * (a0[0] + b0[0]);                          \
    const float sA1 = fnv[1] - 2.f * (a0[1] + b0[1]);                          \
    const float sA2 = fnv[2] - 2.f * (a0[2] + b0[2]);                          \
    const float sA3 = fnv[3] - 2.f * (a0[3] + b0[3]);                          \
    const float sB0 = fnv[0] - 2.f * (a1[0] + b1[0]);                          \
    const float sB1 = fnv[1] - 2.f * (a1[1] + b1[1]);                          \
    const float sB2 = fnv[2] - 2.f * (a1[2] + b1[2]);                          \
    const float sB3 = fnv[3] - 2.f * (a1[3] + b1[3]);                          \
    const int rb4 = (c_) * 64 + (t_) * 16 + hgrp * 4;

#define GATE2(qq_, tau_, s0_, s1_, s2_, s3_) {                                 \
    const float sv_[4] = {s0_, s1_, s2_, s3_};                                 \
    _Pragma("unroll")                                                          \
    for (int j_ = 0; j_ < 4; ++j_) {                                           \
        if (sv_[j_] <= (tau_)) {                                               \
            const int p_ = atomicAdd(&cnt[qq_], 1);                            \
            if (p_ < CAP) {                                                    \
                bufd[(qq_) * CAP + p_] = sv_[j_];                              \
                bufi[(qq_) * CAP + p_] = (unsigned short)(rb4 + j_);           \
            }                                                                  \
        }                                                                      \
    }                                                                          \
}

__global__ __launch_bounds__(1024) void knn_filter32(
    const unsigned short* __restrict__ Fh, const unsigned short* __restrict__ Fl,
    const float* __restrict__ fn,
    const unsigned short* __restrict__ Qh, const unsigned short* __restrict__ Ql,
    const float* __restrict__ qn,
    const float* __restrict__ targets, float* __restrict__ out)
{
    // pool: phase1 = smp u16[32][SMPS] (131.6 KB); phase2/3 = bufd f32[32][CAP]
    // (73.7 KB) + bufi u16[32][CAP] (36.9 KB).
    __shared__ __align__(16) unsigned char pool[QB * SMPS * 2];
    __shared__ float tau_f[QB];
    __shared__ int   cnt[QB];

    unsigned short* smp  = (unsigned short*)pool;
    float*          bufd = (float*)pool;
    unsigned short* bufi = (unsigned short*)(pool + QB * CAP * 4);

    const int tid  = threadIdx.x;
    const int lane = tid & 63;
    const int w    = tid >> 6;          // 0..15
    const int qbase = blockIdx.x * QB;
    const int q    = lane & 15;
    const int hgrp = lane >> 4;
    const int kof  = hgrp * 8;

    if (tid < QB) cnt[tid] = 0;

    // stationary B-operand (Q^T) fragments, two query groups
    const int qrow0 = qbase + q;
    const int qrow1 = qbase + 16 + q;
    const bf16x8 qh0A = *(const bf16x8*)(Qh + (size_t)qrow0 * DD + kof);
    const bf16x8 qh1A = *(const bf16x8*)(Qh + (size_t)qrow0 * DD + kof + 32);
    const bf16x8 ql0A = *(const bf16x8*)(Ql + (size_t)qrow0 * DD + kof);
    const bf16x8 ql1A = *(const bf16x8*)(Ql + (size_t)qrow0 * DD + kof + 32);
    const bf16x8 qh0B = *(const bf16x8*)(Qh + (size_t)qrow1 * DD + kof);
    const bf16x8 qh1B = *(const bf16x8*)(Qh + (size_t)qrow1 * DD + kof + 32);
    const bf16x8 ql0B = *(const bf16x8*)(Ql + (size_t)qrow1 * DD + kof);
    const bf16x8 ql1B = *(const bf16x8*)(Ql + (size_t)qrow1 * DD + kof + 32);

    // ============ phase 1: sample scan (chunks 0..31) -> u16 keys ==========
    #pragma unroll
    for (int cc = 0; cc < 2; ++cc) {
        const int chunk = w * 2 + cc;
        #pragma unroll
        for (int t = 0; t < 4; ++t) {
            SUBTILE2(chunk, t)
            ushort4 kA, kB;
            kA.x = (unsigned short)(enc32(sA0) >> 16);
            kA.y = (unsigned short)(enc32(sA1) >> 16);
            kA.z = (unsigned short)(enc32(sA2) >> 16);
            kA.w = (unsigned short)(enc32(sA3) >> 16);
            kB.x = (unsigned short)(enc32(sB0) >> 16);
            kB.y = (unsigned short)(enc32(sB1) >> 16);
            kB.z = (unsigned short)(enc32(sB2) >> 16);
            kB.w = (unsigned short)(enc32(sB3) >> 16);
            *(ushort4*)&smp[q * SMPS + rb4]        = kA;
            *(ushort4*)&smp[(16 + q) * SMPS + rb4] = kB;
        }
    }
    __syncthreads();

    // ---- tau per query: 16-bit count-select; wave w owns queries 2w, 2w+1
    #pragma unroll
    for (int e = 0; e < 2; ++e) {
        const int qq = w * 2 + e;
        unsigned short vv[32];
        #pragma unroll
        for (int u = 0; u < 32; ++u) vv[u] = smp[qq * SMPS + lane + u * 64];
        unsigned lo = 0;
        #pragma unroll
        for (int bit = 15; bit >= 0; --bit) {
            const unsigned trial = lo | (1u << bit);
            int c = 0;
            #pragma unroll
            for (int u = 0; u < 32; ++u) c += (vv[u] < trial);
            #pragma unroll
            for (int o = 32; o >= 1; o >>= 1) c += __shfl_xor(c, o);
            if (c < KK) lo = trial;
        }
        const float tf = (lo >= 0xFFFFu) ? __builtin_inff()
                                         : dec32((lo + 1u) << 16);
        if (lane == 0) tau_f[qq] = tf;
    }
    __syncthreads();   // smp dead; candidate buffers take over the pool

    // ============ phase 2: full scan, register-tau gated append ============
    const float tauR0 = tau_f[q];
    const float tauR1 = tau_f[16 + q];
    for (int c = w; c < NCH; c += NW) {
        #pragma unroll
        for (int t = 0; t < 4; ++t) {
            SUBTILE2(c, t)
            GATE2(q,      tauR0, sA0, sA1, sA2, sA3)
            GATE2(16 + q, tauR1, sB0, sB1, sB2, sB3)
        }
    }
    __syncthreads();

    // ============ phase 3: exact rank + weighted sum (2 q per wave) ========
    #pragma unroll
    for (int e = 0; e < 2; ++e) {
        const int q3 = w * 2 + e;
        const int n  = min(cnt[q3], CAP);
        const float qnv = qn[qbase + q3];

        float    ms[9]; unsigned kk[9]; unsigned short miu[9];
        #pragma unroll
        for (int u = 0; u < 9; ++u) {
            const int j = lane + u * 64;
            const bool v = (j < n);
            ms[u]  = v ? bufd[q3 * CAP + j] : __builtin_inff();
            miu[u] = v ? bufi[q3 * CAP + j] : (unsigned short)0xFFFFu;
            kk[u]  = enc32(ms[u]);
        }
        unsigned lo = 0;
        for (int bit = 31; bit >= 0; --bit) {
            const unsigned trial = lo | (1u << bit);
            int c = 0;
            #pragma unroll
            for (int u = 0; u < 9; ++u) c += (kk[u] < trial);
            #pragma unroll
            for (int o = 32; o >= 1; o >>= 1) c += __shfl_xor(c, o);
            if (c < KK) lo = trial;
        }
        int c0 = 0, tcnt = 0;
        #pragma unroll
        for (int u = 0; u < 9; ++u) { c0 += (kk[u] < lo); tcnt += (kk[u] == lo); }
        #pragma unroll
        for (int o = 32; o >= 1; o >>= 1) {
            c0 += __shfl_xor(c0, o); tcnt += __shfl_xor(tcnt, o);
        }
        const int kprime = KK - c0;
        unsigned ilo = 0xFFFFu;
        if (tcnt != kprime) {
            ilo = 0;
            for (int bit = 15; bit >= 0; --bit) {
                const unsigned trial = ilo | (1u << bit);
                int c = 0;
                #pragma unroll
                for (int u = 0; u < 9; ++u)
                    c += ((kk[u] == lo) && ((unsigned)miu[u] < trial));
                #pragma unroll
                for (int o = 32; o >= 1; o >>= 1) c += __shfl_xor(c, o);
                if (c < kprime) ilo = trial;
            }
        }
        float nume = 0.f, deno = 0.f;
        #pragma unroll
        for (int u = 0; u < 9; ++u) {
            const bool inc = (kk[u] < lo) ||
                             ((kk[u] == lo) && ((unsigned)miu[u] <= ilo));
            if (inc) {
                const float d2 = fmaxf(qnv + ms[u], 0.f);
                const float wv = 1.f / (d2 + 1e-4f);
                nume = fmaf(wv, targets[miu[u]], nume);
                deno += wv;
            }
        }
        #pragma unroll
        for (int o = 32; o >= 1; o >>= 1) {
            nume += __shfl_xor(nume, o);
            deno += __shfl_xor(deno, o);
        }
        if (lane == 0) out[qbase + q3] = nume / fmaxf(deno, 1e-9f);
    }
}

// ---------------- fallback: round-1 exact fp32 vector kernel ----------------
#define BQ 32
#define WQ 8
__global__ __launch_bounds__(256) void hp_knn_kernel(
    const float* __restrict__ points, const float* __restrict__ features,
    const float* __restrict__ targets, float* __restrict__ out)
{
    __shared__ __align__(16) float Qs[BQ][DD];
    __shared__ float qn_s[BQ];
    __shared__ float topd[BQ][KK];
    __shared__ int   topi[BQ][KK];
    const int tid = threadIdx.x, lane = tid & 63, wv = tid >> 6, qb = wv * WQ;
    {
        const float4* src = (const float4*)(points + (size_t)blockIdx.x * BQ * DD);
        float4* dst = (float4*)&Qs[0][0];
        #pragma unroll
        for (int i = 0; i < (BQ * DD / 4) / 256; ++i) dst[tid + i * 256] = src[tid + i * 256];
    }
    for (int i = tid; i < BQ * KK; i += 256) { (&topd[0][0])[i] = __builtin_inff(); (&topi[0][0])[i] = 0; }
    __syncthreads();
    if (tid < BQ) {
        float s = 0.f;
        #pragma unroll
        for (int d = 0; d < DD; ++d) s = fmaf(Qs[tid][d], Qs[tid][d], s);
        qn_s[tid] = s;
    }
    __syncthreads();
    for (int c = 0; c < (MM + 63) / 64; ++c) {
        const int m = c * 64 + lane, mc = (m < MM) ? m : (MM - 1);
        float f[DD];
        const float4* fr = (const float4*)(features + (size_t)mc * DD);
        #pragma unroll
        for (int b = 0; b < DD / 4; ++b) { float4 v = fr[b]; f[4*b]=v.x; f[4*b+1]=v.y; f[4*b+2]=v.z; f[4*b+3]=v.w; }
        float fnv = 0.f;
        #pragma unroll
        for (int d = 0; d < DD; ++d) fnv = fmaf(f[d], f[d], fnv);
        float d2v[WQ];
        #pragma unroll
        for (int qi = 0; qi < WQ; ++qi) {
            const float4* qr = (const float4*)&Qs[qb + qi][0];
            float a0=0,a1=0,a2=0,a3=0;
            #pragma unroll
            for (int b = 0; b < DD / 4; ++b) {
                float4 q4 = qr[b];
                a0 = fmaf(q4.x, f[4*b], a0); a1 = fmaf(q4.y, f[4*b+1], a1);
                a2 = fmaf(q4.z, f[4*b+2], a2); a3 = fmaf(q4.w, f[4*b+3], a3);
            }
            float d2 = fmaxf(qn_s[qb+qi] + fnv - 2.f*((a0+a1)+(a2+a3)), 0.f);
            d2v[qi] = (m < MM) ? d2 : __builtin_inff();
        }
        #pragma unroll
        for (int qi = 0; qi < WQ; ++qi) {
            const int q = qb + qi;
            unsigned long long ball = __ballot(d2v[qi] < topd[q][KK-1]);
            while (ball) {
                const int j = __builtin_ctzll(ball); ball &= ball - 1;
                const float dval = __shfl(d2v[qi], j); const int mval = c * 64 + j;
                if (lane < KK) {
                    const float cur = topd[q][lane];
                    if (cur > dval) {
                        const float pd = (lane > 0) ? topd[q][lane-1] : -1.f;
                        const int   pi = (lane > 0) ? topi[q][lane-1] : 0;
                        const bool tp = (pd > dval);
                        topd[q][lane] = tp ? pd : dval; topi[q][lane] = tp ? pi : mval;
                    }
                }
            }
        }
    }
    #pragma unroll
    for (int qi = 0; qi < WQ; ++qi) {
        const int q = qb + qi;
        float wsum = 0.f, wt = 0.f;
        if (lane < KK) {
            const float ww = 1.f / (topd[q][lane] + 1e-4f);
            wsum = ww; wt = ww * targets[topi[q][lane]];
        }
        #pragma unroll
        for (int o = 32; o >= 1; o >>= 1) { wsum += __shfl_xor(wsum, o); wt += __shfl_xor(wt, o); }
        if (lane == 0) out[(size_t)blockIdx.x * BQ + q] = wt / fmaxf(wsum, 1e-9f);
    }
}

extern "C" void kernel_launch(void* const* d_in, const int* in_sizes, int n_in,
                              void* d_out, int out_size, void* d_ws, size_t ws_size,
                              hipStream_t stream) {
    const float* points   = (const float*)d_in[0];
    const float* features = (const float*)d_in[1];
    const float* targets  = (const float*)d_in[2];
    float* out = (float*)d_out;

    if (ws_size < (size_t)WS_REQ) {
        hp_knn_kernel<<<dim3(NQ / BQ), dim3(256), 0, stream>>>(points, features, targets, out);
        return;
    }
    char* ws = (char*)d_ws;
    unsigned short* Fh = (unsigned short*)(ws + OFF_FH);
    unsigned short* Fl = (unsigned short*)(ws + OFF_FL);
    float*          fn = (float*)(ws + OFF_FN);
    unsigned short* Qh = (unsigned short*)(ws + OFF_QH);
    unsigned short* Ql = (unsigned short*)(ws + OFF_QL);
    float*          qnp= (float*)(ws + OFF_QN);

    prep_split<<<dim3(MPAD * DD / 256), dim3(256), 0, stream>>>(features, Fh, Fl, fn, MM);
    prep_split<<<dim3(NQ * DD / 256),  dim3(256), 0, stream>>>(points,   Qh, Ql, qnp, NQ);
    knn_filter32<<<dim3(NQ / QB), dim3(1024), 0, stream>>>(Fh, Fl, fn, Qh, Ql, qnp, targets, out);
}